// Round 1
// baseline (1535.122 us; speedup 1.0000x reference)
//
#include <hip/hip_runtime.h>
#include <hip/hip_bf16.h>
#include <math.h>

// Problem dims: B=2, S=64, C=64, NH=8, NHC=512, H=W=32, M1=M2=16 (256 modes)
// Mode m = p*16+q, p = kx in [0,16), q = ky in [0,16).
// y(x,j) = (1/1024) Re sum_m c_q Z_m w^(p x + q j), c_0=1, c_{q>=1}=2.
// Score mode weight lambda: DC: 1 (real parts only), (p>=1,q=0): 0.5, q>=1: 2.
// V-path per-mode factor mu = T*c: DC: 1 (zero imag), (p>=1,q=0): 0.5, q>=1: 2.

#define PI_F 3.14159265358979323846f

// ---------------- K1: forward DFT of seq at 16x16 modes ----------------
// grid 8192 = (b*64+s)*64+i fields, 256 threads. Writes Xf[b][m][s][i] (float2)
__global__ __launch_bounds__(256) void k_dft(const float* __restrict__ seq,
                                             float2* __restrict__ Xf) {
  __shared__ float fld[32][33];
  __shared__ float2 tb[32][17];
  __shared__ float2 tw[32];
  int f = blockIdx.x;
  int tid = threadIdx.x;
  if (tid < 32) {
    float a = (2.0f * PI_F / 32.0f) * (float)tid;
    tw[tid] = make_float2(cosf(a), sinf(a));
  }
  const float4* s4 = (const float4*)(seq + (size_t)f * 1024);
  float4 v = s4[tid];
  int x0 = tid >> 3, y0 = (tid & 7) * 4;
  fld[x0][y0 + 0] = v.x; fld[x0][y0 + 1] = v.y;
  fld[x0][y0 + 2] = v.z; fld[x0][y0 + 3] = v.w;
  __syncthreads();
  // stage A: t[x][q] = sum_y fld[x][y] * e^{-i 2pi q y/32}
  for (int o = tid; o < 512; o += 256) {
    int x = o >> 4, q = o & 15;
    float re = 0.f, im = 0.f;
#pragma unroll
    for (int y = 0; y < 32; ++y) {
      float val = fld[x][y];
      float2 w = tw[(q * y) & 31];
      re = fmaf(val, w.x, re);
      im = fmaf(val, -w.y, im);
    }
    tb[x][q] = make_float2(re, im);
  }
  __syncthreads();
  // stage B: Xf[p][q] = sum_x e^{-i 2pi p x/32} * t[x][q]
  int p = tid >> 4, q = tid & 15;
  float re = 0.f, im = 0.f;
#pragma unroll
  for (int x = 0; x < 32; ++x) {
    float2 t = tb[x][q];
    float2 w = tw[(p * x) & 31];
    re += w.x * t.x + w.y * t.y;
    im += w.x * t.y - w.y * t.x;
  }
  int b = f >> 12;
  int si = f & 4095;  // s*64+i
  Xf[((size_t)(b * 256 + tid)) * 4096 + si] = make_float2(re, im);
}

// ---------------- K2: fused Q/K projection + partial scores ----------------
// grid (32 chunks, NH, B), 256 threads. scores[b][h][s][t] += lambda-weighted.
__global__ __launch_bounds__(256) void k_scores(const float2* __restrict__ Xf,
                                                const float* __restrict__ wq_,
                                                const float* __restrict__ wk_,
                                                float* __restrict__ scores) {
  __shared__ float2 Xs[64][65];
  __shared__ float2 Wb[64][65];
  __shared__ float2 Qb[64][65];
  __shared__ float2 Kb[64][65];
  const float2* wq = (const float2*)wq_;
  const float2* wk = (const float2*)wk_;
  int chunk = blockIdx.x, h = blockIdx.y, b = blockIdx.z;
  int tid = threadIdx.x;
  int g0 = tid >> 4, g1 = tid & 15;
  int r0 = g0 * 4, c0 = g1 * 4;
  float sc[4][4] = {};
  for (int mm = 0; mm < 8; ++mm) {
    int m = chunk * 8 + mm;
    __syncthreads();
    {
      const float2* xs = Xf + ((size_t)b * 256 + m) * 4096;
      for (int k = tid; k < 4096; k += 256) Xs[k >> 6][k & 63] = xs[k];
      for (int k = tid; k < 4096; k += 256) {
        int i = k >> 6, d = k & 63;
        Wb[i][d] = wq[((size_t)i * 512 + h * 64 + d) * 256 + m];
      }
    }
    __syncthreads();
    // Q = X * Wq (complex), fold lambda, zero imag at DC
    {
      float qr[4][4] = {}, qi[4][4] = {};
      for (int i = 0; i < 64; ++i) {
        float2 xv[4], wv[4];
#pragma unroll
        for (int a = 0; a < 4; ++a) xv[a] = Xs[r0 + a][i];
#pragma unroll
        for (int c = 0; c < 4; ++c) wv[c] = Wb[i][c0 + c];
#pragma unroll
        for (int a = 0; a < 4; ++a)
#pragma unroll
          for (int c = 0; c < 4; ++c) {
            qr[a][c] = fmaf(xv[a].x, wv[c].x, qr[a][c]);
            qr[a][c] = fmaf(-xv[a].y, wv[c].y, qr[a][c]);
            qi[a][c] = fmaf(xv[a].x, wv[c].y, qi[a][c]);
            qi[a][c] = fmaf(xv[a].y, wv[c].x, qi[a][c]);
          }
      }
      float lam = (m == 0) ? 1.0f : (((m & 15) == 0) ? 0.5f : 2.0f);
#pragma unroll
      for (int a = 0; a < 4; ++a)
#pragma unroll
        for (int c = 0; c < 4; ++c)
          Qb[r0 + a][c0 + c] =
              make_float2(qr[a][c] * lam, (m == 0) ? 0.0f : qi[a][c] * lam);
    }
    __syncthreads();
    for (int k = tid; k < 4096; k += 256) {
      int i = k >> 6, d = k & 63;
      Wb[i][d] = wk[((size_t)i * 512 + h * 64 + d) * 256 + m];
    }
    __syncthreads();
    // K = X * Wk (complex)
    {
      float qr[4][4] = {}, qi[4][4] = {};
      for (int i = 0; i < 64; ++i) {
        float2 xv[4], wv[4];
#pragma unroll
        for (int a = 0; a < 4; ++a) xv[a] = Xs[r0 + a][i];
#pragma unroll
        for (int c = 0; c < 4; ++c) wv[c] = Wb[i][c0 + c];
#pragma unroll
        for (int a = 0; a < 4; ++a)
#pragma unroll
          for (int c = 0; c < 4; ++c) {
            qr[a][c] = fmaf(xv[a].x, wv[c].x, qr[a][c]);
            qr[a][c] = fmaf(-xv[a].y, wv[c].y, qr[a][c]);
            qi[a][c] = fmaf(xv[a].x, wv[c].y, qi[a][c]);
            qi[a][c] = fmaf(xv[a].y, wv[c].x, qi[a][c]);
          }
      }
#pragma unroll
      for (int a = 0; a < 4; ++a)
#pragma unroll
        for (int c = 0; c < 4; ++c)
          Kb[r0 + a][c0 + c] = make_float2(qr[a][c], qi[a][c]);
    }
    __syncthreads();
    // partial scores: sc[s][t] += sum_d Re(Q[s][d] * conj(K[t][d]))
    {
      for (int d = 0; d < 64; ++d) {
        float2 qv[4], kv[4];
#pragma unroll
        for (int a = 0; a < 4; ++a) qv[a] = Qb[r0 + a][d];
#pragma unroll
        for (int c = 0; c < 4; ++c) kv[c] = Kb[c0 + c][d];
#pragma unroll
        for (int a = 0; a < 4; ++a)
#pragma unroll
          for (int c = 0; c < 4; ++c)
            sc[a][c] =
                fmaf(qv[a].x, kv[c].x, fmaf(qv[a].y, kv[c].y, sc[a][c]));
      }
    }
  }
  const float fac = 1.0f / 262144.0f;  // (1/1024)*(1/256)
  float* dst = scores + ((size_t)(b * 8 + h)) * 4096;
#pragma unroll
  for (int a = 0; a < 4; ++a)
#pragma unroll
    for (int c = 0; c < 4; ++c)
      atomicAdd(&dst[(r0 + a) * 64 + (c0 + c)], sc[a][c] * fac);
}

// ---------------- K3: log-CPB bias + softmax (in place) ----------------
// grid 1024 = (b*8+h)*64+s rows, 64 threads (1 wave), lane = t.
__global__ __launch_bounds__(64) void k_softmax(float* __restrict__ scores,
                                                const float* __restrict__ w1,
                                                const float* __restrict__ b1,
                                                const float* __restrict__ w2,
                                                const float* __restrict__ b2) {
  int id = blockIdx.x;
  int s = id & 63;
  int h = (id >> 6) & 7;
  int t = threadIdx.x;
  float d0 = (float)((s >> 3) - (t >> 3)) * (8.0f / 7.0f);
  float d1 = (float)((s & 7) - (t & 7)) * (8.0f / 7.0f);
  float a0 = log2f(fabsf(d0) + 1.0f) * (1.0f / 3.0f);
  float a1 = log2f(fabsf(d1) + 1.0f) * (1.0f / 3.0f);
  float r0 = (d0 < 0.f) ? -a0 : a0;
  float r1 = (d1 < 0.f) ? -a1 : a1;
  float acc = b2[h];
  for (int c = 0; c < 64; ++c) {
    float hv = fmaf(r0, w1[c], fmaf(r1, w1[64 + c], b1[c]));
    hv = fmaxf(hv, 0.0f);
    acc = fmaf(hv, w2[c * 8 + h], acc);
  }
  float bias = 16.0f / (1.0f + expf(-acc));
  size_t base = (size_t)id * 64;
  float v = scores[base + t] + bias;
  float mx = v;
  for (int o = 32; o; o >>= 1) mx = fmaxf(mx, __shfl_xor(mx, o));
  float e = expf(v - mx);
  float sm = e;
  for (int o = 32; o; o >>= 1) sm += __shfl_xor(sm, o);
  scores[base + t] = e / sm;
}

// ---------------- K4: fused V projection + attn mix + Wo ----------------
// grid (256 modes, B), 256 threads. Ff[b][s][c][m] (float2)
__global__ __launch_bounds__(256) void k_vpath(const float2* __restrict__ Xf,
                                               const float* __restrict__ wv_,
                                               const float* __restrict__ wo_,
                                               const float* __restrict__ attn,
                                               float2* __restrict__ Ff) {
  __shared__ float2 Xs[64][65];
  __shared__ float2 Wb[64][65];
  __shared__ float2 Vb[64][65];
  __shared__ float2 Yb[64][65];
  __shared__ float At[64][65];
  const float2* wv = (const float2*)wv_;
  const float2* wo = (const float2*)wo_;
  int m = blockIdx.x, b = blockIdx.y;
  int tid = threadIdx.x;
  int g0 = tid >> 4, g1 = tid & 15;
  int r0 = g0 * 4, c0 = g1 * 4;
  const float2* xs = Xf + ((size_t)b * 256 + m) * 4096;
  for (int k = tid; k < 4096; k += 256) Xs[k >> 6][k & 63] = xs[k];
  float fr[4][4] = {}, fi[4][4] = {};
  float mu = (m == 0) ? 1.0f : (((m & 15) == 0) ? 0.5f : 2.0f);
  for (int h = 0; h < 8; ++h) {
    __syncthreads();
    const float* at = attn + ((size_t)(b * 8 + h)) * 4096;
    for (int k = tid; k < 4096; k += 256) At[k >> 6][k & 63] = at[k];
    for (int k = tid; k < 4096; k += 256) {
      int i = k >> 6, d = k & 63;
      Wb[i][d] = wv[((size_t)i * 512 + h * 64 + d) * 256 + m];
    }
    __syncthreads();
    // V[t][d] = sum_i X[t][i]*Wv[i][d], scaled by mu (DC: zero imag)
    {
      float vr[4][4] = {}, vi[4][4] = {};
      for (int i = 0; i < 64; ++i) {
        float2 xv[4], wvv[4];
#pragma unroll
        for (int a = 0; a < 4; ++a) xv[a] = Xs[r0 + a][i];
#pragma unroll
        for (int c = 0; c < 4; ++c) wvv[c] = Wb[i][c0 + c];
#pragma unroll
        for (int a = 0; a < 4; ++a)
#pragma unroll
          for (int c = 0; c < 4; ++c) {
            vr[a][c] = fmaf(xv[a].x, wvv[c].x, vr[a][c]);
            vr[a][c] = fmaf(-xv[a].y, wvv[c].y, vr[a][c]);
            vi[a][c] = fmaf(xv[a].x, wvv[c].y, vi[a][c]);
            vi[a][c] = fmaf(xv[a].y, wvv[c].x, vi[a][c]);
          }
      }
#pragma unroll
      for (int a = 0; a < 4; ++a)
#pragma unroll
        for (int c = 0; c < 4; ++c)
          Vb[r0 + a][c0 + c] = make_float2(vr[a][c] * mu,
                                           (m == 0) ? 0.0f : vi[a][c] * mu);
    }
    __syncthreads();
    // load Wo tile [d][c] (independent of Y compute below)
    for (int k = tid; k < 4096; k += 256) {
      int d = k >> 6, c = k & 63;
      Wb[d][c] = wo[((size_t)(h * 64 + d) * 64 + c) * 256 + m];
    }
    // Y[s][d] = sum_t At[s][t] * V[t][d]
    {
      float yr[4][4] = {}, yi[4][4] = {};
      for (int t = 0; t < 64; ++t) {
        float av[4];
        float2 vv[4];
#pragma unroll
        for (int a = 0; a < 4; ++a) av[a] = At[r0 + a][t];
#pragma unroll
        for (int c = 0; c < 4; ++c) vv[c] = Vb[t][c0 + c];
#pragma unroll
        for (int a = 0; a < 4; ++a)
#pragma unroll
          for (int c = 0; c < 4; ++c) {
            yr[a][c] = fmaf(av[a], vv[c].x, yr[a][c]);
            yi[a][c] = fmaf(av[a], vv[c].y, yi[a][c]);
          }
      }
#pragma unroll
      for (int a = 0; a < 4; ++a)
#pragma unroll
        for (int c = 0; c < 4; ++c)
          Yb[r0 + a][c0 + c] = make_float2(yr[a][c], yi[a][c]);
    }
    __syncthreads();
    // Ff[s][c] += sum_d Y[s][d] * Wo[d][c] (complex)
    {
      for (int d = 0; d < 64; ++d) {
        float2 yv[4], wv2[4];
#pragma unroll
        for (int a = 0; a < 4; ++a) yv[a] = Yb[r0 + a][d];
#pragma unroll
        for (int c = 0; c < 4; ++c) wv2[c] = Wb[d][c0 + c];
#pragma unroll
        for (int a = 0; a < 4; ++a)
#pragma unroll
          for (int c = 0; c < 4; ++c) {
            fr[a][c] = fmaf(yv[a].x, wv2[c].x, fr[a][c]);
            fr[a][c] = fmaf(-yv[a].y, wv2[c].y, fr[a][c]);
            fi[a][c] = fmaf(yv[a].x, wv2[c].y, fi[a][c]);
            fi[a][c] = fmaf(yv[a].y, wv2[c].x, fi[a][c]);
          }
      }
    }
  }
#pragma unroll
  for (int a = 0; a < 4; ++a)
#pragma unroll
    for (int c = 0; c < 4; ++c)
      Ff[(((size_t)b * 64 + r0 + a) * 64 + (c0 + c)) * 256 + m] =
          make_float2(fr[a][c], fi[a][c]);
}

// ---------------- K5: inverse DFT to real field ----------------
// grid 8192 = (b*64+s)*64+c fields, 256 threads.
__global__ __launch_bounds__(256) void k_idft(const float2* __restrict__ Ff,
                                              float* __restrict__ out) {
  __shared__ float2 Fm[256];
  __shared__ float2 g[32][17];
  __shared__ float2 tw[32];
  int f = blockIdx.x;
  int tid = threadIdx.x;
  if (tid < 32) {
    float a = (2.0f * PI_F / 32.0f) * (float)tid;
    tw[tid] = make_float2(cosf(a), sinf(a));
  }
  Fm[tid] = Ff[(size_t)f * 256 + tid];
  __syncthreads();
  // stage A: g[x][q] = sum_p Fm[p*16+q] * e^{+i 2pi p x/32}
  for (int o = tid; o < 512; o += 256) {
    int x = o >> 4, q = o & 15;
    float gr = 0.f, gi = 0.f;
#pragma unroll
    for (int p = 0; p < 16; ++p) {
      float2 a = Fm[p * 16 + q];
      float2 w = tw[(p * x) & 31];
      gr += a.x * w.x - a.y * w.y;
      gi += a.x * w.y + a.y * w.x;
    }
    g[x][q] = make_float2(gr, gi);
  }
  __syncthreads();
  // stage B: out[x][j] = (1/1024) sum_q (gr*cos(qj) - gi*sin(qj))
  int x = tid >> 3, j0 = (tid & 7) * 4;
  float4 r;
  float* rr = &r.x;
#pragma unroll
  for (int jj = 0; jj < 4; ++jj) {
    int j = j0 + jj;
    float acc = 0.f;
#pragma unroll
    for (int q = 0; q < 16; ++q) {
      float2 gv = g[x][q];
      float2 w = tw[(q * j) & 31];
      acc += gv.x * w.x - gv.y * w.y;
    }
    rr[jj] = acc * (1.0f / 1024.0f);
  }
  *(float4*)(out + (size_t)f * 1024 + x * 32 + j0) = r;
}

extern "C" void kernel_launch(void* const* d_in, const int* in_sizes, int n_in,
                              void* d_out, int out_size, void* d_ws,
                              size_t ws_size, hipStream_t stream) {
  const float* seq = (const float*)d_in[0];
  const float* wq = (const float*)d_in[1];
  const float* wk = (const float*)d_in[2];
  const float* wv = (const float*)d_in[3];
  const float* wo = (const float*)d_in[4];
  const float* w1 = (const float*)d_in[5];
  const float* b1 = (const float*)d_in[6];
  const float* w2 = (const float*)d_in[7];
  const float* b2 = (const float*)d_in[8];
  float* out = (float*)d_out;

  char* ws = (char*)d_ws;
  float2* Xf = (float2*)(ws);                       // 16,777,216 B
  float* scores = (float*)(ws + 16777216);          //    262,144 B
  float2* Ff = (float2*)(ws + 16777216 + 262144);   // 16,777,216 B

  hipMemsetAsync(scores, 0, 262144, stream);
  k_dft<<<8192, 256, 0, stream>>>(seq, Xf);
  k_scores<<<dim3(32, 8, 2), 256, 0, stream>>>(Xf, wq, wk, scores);
  k_softmax<<<1024, 64, 0, stream>>>(scores, w1, b1, w2, b2);
  k_vpath<<<dim3(256, 2), 256, 0, stream>>>(Xf, wv, wo, scores, Ff);
  k_idft<<<8192, 256, 0, stream>>>(Ff, out);
}

// Round 2
// 1336.078 us; speedup vs baseline: 1.1490x; 1.1490x over previous
//
#include <hip/hip_runtime.h>
#include <hip/hip_bf16.h>
#include <math.h>

// Problem dims: B=2, S=64, C=64, NH=8, NHC=512, H=W=32, M1=M2=16 (256 modes)
// Mode m = p*16+q. Score mode weight lambda / V-path factor mu:
//   DC (m==0): 1 (imag zeroed), (p>=1,q==0) i.e. m%16==0: 0.5, q>=1: 2.

#define PI_F 3.14159265358979323846f

// ---------------- K1: forward DFT of seq at 16x16 modes ----------------
__global__ __launch_bounds__(256) void k_dft(const float* __restrict__ seq,
                                             float2* __restrict__ Xf) {
  __shared__ float fld[32][33];
  __shared__ float2 tb[32][17];
  __shared__ float2 tw[32];
  int f = blockIdx.x;
  int tid = threadIdx.x;
  if (tid < 32) {
    float a = (2.0f * PI_F / 32.0f) * (float)tid;
    tw[tid] = make_float2(cosf(a), sinf(a));
  }
  const float4* s4 = (const float4*)(seq + (size_t)f * 1024);
  float4 v = s4[tid];
  int x0 = tid >> 3, y0 = (tid & 7) * 4;
  fld[x0][y0 + 0] = v.x; fld[x0][y0 + 1] = v.y;
  fld[x0][y0 + 2] = v.z; fld[x0][y0 + 3] = v.w;
  __syncthreads();
  for (int o = tid; o < 512; o += 256) {
    int x = o >> 4, q = o & 15;
    float re = 0.f, im = 0.f;
#pragma unroll
    for (int y = 0; y < 32; ++y) {
      float val = fld[x][y];
      float2 w = tw[(q * y) & 31];
      re = fmaf(val, w.x, re);
      im = fmaf(val, -w.y, im);
    }
    tb[x][q] = make_float2(re, im);
  }
  __syncthreads();
  int p = tid >> 4, q = tid & 15;
  float re = 0.f, im = 0.f;
#pragma unroll
  for (int x = 0; x < 32; ++x) {
    float2 t = tb[x][q];
    float2 w = tw[(p * x) & 31];
    re += w.x * t.x + w.y * t.y;
    im += w.x * t.y - w.y * t.x;
  }
  int b = f >> 12;
  int si = f & 4095;
  Xf[((size_t)(b * 256 + tid)) * 4096 + si] = make_float2(re, im);
}

// ---------------- K-repack: [r][256] -> [m][32768] (float2) ----------------
// grid 512 x 256. Reads coalesced along m; each lane writes a 512B run.
__global__ __launch_bounds__(256) void k_repack(const float2* __restrict__ in,
                                                float2* __restrict__ out) {
  int r0 = blockIdx.x * 64;
  int m = threadIdx.x;
  for (int rr = 0; rr < 64; ++rr) {
    int r = r0 + rr;
    out[(size_t)m * 32768 + r] = in[(size_t)r * 256 + m];
  }
}

// ---------------- K2r: fused Q/K projection + partial scores (repacked W) --
// grid (32 chunks, NH, B), 256 threads. Interleaved tiling s=g0+16a, t=g1+16c.
__global__ __launch_bounds__(256) void k_scores_r(
    const float2* __restrict__ Xf, const float2* __restrict__ Rq,
    const float2* __restrict__ Rk, float* __restrict__ scores) {
  __shared__ float2 Xs[64][65];
  __shared__ float2 Wb[64][65];
  __shared__ float2 Qb[64][65];
  __shared__ float2 Kb[64][65];
  int chunk = blockIdx.x, h = blockIdx.y, b = blockIdx.z;
  int tid = threadIdx.x;
  int g0 = tid >> 4, g1 = tid & 15;
  int hd0 = h * 64;
  float sc[4][4] = {};
  for (int mm = 0; mm < 8; ++mm) {
    int m = chunk * 8 + mm;
    __syncthreads();
    {
      const float2* xs = Xf + ((size_t)b * 256 + m) * 4096;
      const float2* wq = Rq + (size_t)m * 32768 + hd0;
      for (int k = tid; k < 4096; k += 256) Xs[k >> 6][k & 63] = xs[k];
      for (int k = tid; k < 4096; k += 256)
        Wb[k >> 6][k & 63] = wq[(size_t)(k >> 6) * 512 + (k & 63)];
    }
    __syncthreads();
    // Q = X * Wq (complex), fold lambda, zero imag at DC
    {
      float qr[4][4] = {}, qi[4][4] = {};
#pragma unroll 4
      for (int i = 0; i < 64; ++i) {
        float2 xv[4], wv[4];
#pragma unroll
        for (int a = 0; a < 4; ++a) xv[a] = Xs[g0 + 16 * a][i];
#pragma unroll
        for (int c = 0; c < 4; ++c) wv[c] = Wb[i][g1 + 16 * c];
#pragma unroll
        for (int a = 0; a < 4; ++a)
#pragma unroll
          for (int c = 0; c < 4; ++c) {
            qr[a][c] = fmaf(xv[a].x, wv[c].x, qr[a][c]);
            qr[a][c] = fmaf(-xv[a].y, wv[c].y, qr[a][c]);
            qi[a][c] = fmaf(xv[a].x, wv[c].y, qi[a][c]);
            qi[a][c] = fmaf(xv[a].y, wv[c].x, qi[a][c]);
          }
      }
      float lam = (m == 0) ? 1.0f : (((m & 15) == 0) ? 0.5f : 2.0f);
#pragma unroll
      for (int a = 0; a < 4; ++a)
#pragma unroll
        for (int c = 0; c < 4; ++c)
          Qb[g0 + 16 * a][g1 + 16 * c] =
              make_float2(qr[a][c] * lam, (m == 0) ? 0.0f : qi[a][c] * lam);
    }
    __syncthreads();
    {
      const float2* wk = Rk + (size_t)m * 32768 + hd0;
      for (int k = tid; k < 4096; k += 256)
        Wb[k >> 6][k & 63] = wk[(size_t)(k >> 6) * 512 + (k & 63)];
    }
    __syncthreads();
    // K = X * Wk (complex)
    {
      float kr[4][4] = {}, ki[4][4] = {};
#pragma unroll 4
      for (int i = 0; i < 64; ++i) {
        float2 xv[4], wv[4];
#pragma unroll
        for (int a = 0; a < 4; ++a) xv[a] = Xs[g0 + 16 * a][i];
#pragma unroll
        for (int c = 0; c < 4; ++c) wv[c] = Wb[i][g1 + 16 * c];
#pragma unroll
        for (int a = 0; a < 4; ++a)
#pragma unroll
          for (int c = 0; c < 4; ++c) {
            kr[a][c] = fmaf(xv[a].x, wv[c].x, kr[a][c]);
            kr[a][c] = fmaf(-xv[a].y, wv[c].y, kr[a][c]);
            ki[a][c] = fmaf(xv[a].x, wv[c].y, ki[a][c]);
            ki[a][c] = fmaf(xv[a].y, wv[c].x, ki[a][c]);
          }
      }
#pragma unroll
      for (int a = 0; a < 4; ++a)
#pragma unroll
        for (int c = 0; c < 4; ++c)
          Kb[g0 + 16 * a][g1 + 16 * c] = make_float2(kr[a][c], ki[a][c]);
    }
    __syncthreads();
    // partial scores: sc[s][t] += sum_d Re(Q[s][d] * conj(K[t][d]))
    {
#pragma unroll 4
      for (int d = 0; d < 64; ++d) {
        float2 qv[4], kv[4];
#pragma unroll
        for (int a = 0; a < 4; ++a) qv[a] = Qb[g0 + 16 * a][d];
#pragma unroll
        for (int c = 0; c < 4; ++c) kv[c] = Kb[g1 + 16 * c][d];
#pragma unroll
        for (int a = 0; a < 4; ++a)
#pragma unroll
          for (int c = 0; c < 4; ++c)
            sc[a][c] =
                fmaf(qv[a].x, kv[c].x, fmaf(qv[a].y, kv[c].y, sc[a][c]));
      }
    }
  }
  const float fac = 1.0f / 262144.0f;
  float* dst = scores + ((size_t)(b * 8 + h)) * 4096;
#pragma unroll
  for (int a = 0; a < 4; ++a)
#pragma unroll
    for (int c = 0; c < 4; ++c)
      atomicAdd(&dst[(g0 + 16 * a) * 64 + (g1 + 16 * c)], sc[a][c] * fac);
}

// ---------------- K3: log-CPB bias + softmax (in place) ----------------
__global__ __launch_bounds__(64) void k_softmax(float* __restrict__ scores,
                                                const float* __restrict__ w1,
                                                const float* __restrict__ b1,
                                                const float* __restrict__ w2,
                                                const float* __restrict__ b2) {
  int id = blockIdx.x;
  int s = id & 63;
  int h = (id >> 6) & 7;
  int t = threadIdx.x;
  float d0 = (float)((s >> 3) - (t >> 3)) * (8.0f / 7.0f);
  float d1 = (float)((s & 7) - (t & 7)) * (8.0f / 7.0f);
  float a0 = log2f(fabsf(d0) + 1.0f) * (1.0f / 3.0f);
  float a1 = log2f(fabsf(d1) + 1.0f) * (1.0f / 3.0f);
  float r0 = (d0 < 0.f) ? -a0 : a0;
  float r1 = (d1 < 0.f) ? -a1 : a1;
  float acc = b2[h];
  for (int c = 0; c < 64; ++c) {
    float hv = fmaf(r0, w1[c], fmaf(r1, w1[64 + c], b1[c]));
    hv = fmaxf(hv, 0.0f);
    acc = fmaf(hv, w2[c * 8 + h], acc);
  }
  float bias = 16.0f / (1.0f + expf(-acc));
  size_t base = (size_t)id * 64;
  float v = scores[base + t] + bias;
  float mx = v;
  for (int o = 32; o; o >>= 1) mx = fmaxf(mx, __shfl_xor(mx, o));
  float e = expf(v - mx);
  float sm = e;
  for (int o = 32; o; o >>= 1) sm += __shfl_xor(sm, o);
  scores[base + t] = e / sm;
}

// ---------------- K4r: fused V projection + attn mix + Wo (repacked W) -----
__global__ __launch_bounds__(256) void k_vpath_r(
    const float2* __restrict__ Xf, const float2* __restrict__ Rv,
    const float2* __restrict__ Rwo, const float* __restrict__ attn,
    float2* __restrict__ Ff) {
  __shared__ float2 Xs[64][65];
  __shared__ float2 Wb[64][65];
  __shared__ float2 Vb[64][65];
  __shared__ float2 Yb[64][65];
  __shared__ float At[64][65];
  int m = blockIdx.x, b = blockIdx.y;
  int tid = threadIdx.x;
  int g0 = tid >> 4, g1 = tid & 15;
  const float2* xs = Xf + ((size_t)b * 256 + m) * 4096;
  for (int k = tid; k < 4096; k += 256) Xs[k >> 6][k & 63] = xs[k];
  float fr[4][4] = {}, fi[4][4] = {};
  float mu = (m == 0) ? 1.0f : (((m & 15) == 0) ? 0.5f : 2.0f);
  for (int h = 0; h < 8; ++h) {
    __syncthreads();
    const float* at = attn + ((size_t)(b * 8 + h)) * 4096;
    const float2* wv = Rv + (size_t)m * 32768 + h * 64;
    for (int k = tid; k < 4096; k += 256) At[k >> 6][k & 63] = at[k];
    for (int k = tid; k < 4096; k += 256)
      Wb[k >> 6][k & 63] = wv[(size_t)(k >> 6) * 512 + (k & 63)];
    __syncthreads();
    // V[t][d] = mu * sum_i X[t][i]*Wv[i][d] (DC: zero imag)
    {
      float vr[4][4] = {}, vi[4][4] = {};
#pragma unroll 4
      for (int i = 0; i < 64; ++i) {
        float2 xv[4], wvv[4];
#pragma unroll
        for (int a = 0; a < 4; ++a) xv[a] = Xs[g0 + 16 * a][i];
#pragma unroll
        for (int c = 0; c < 4; ++c) wvv[c] = Wb[i][g1 + 16 * c];
#pragma unroll
        for (int a = 0; a < 4; ++a)
#pragma unroll
          for (int c = 0; c < 4; ++c) {
            vr[a][c] = fmaf(xv[a].x, wvv[c].x, vr[a][c]);
            vr[a][c] = fmaf(-xv[a].y, wvv[c].y, vr[a][c]);
            vi[a][c] = fmaf(xv[a].x, wvv[c].y, vi[a][c]);
            vi[a][c] = fmaf(xv[a].y, wvv[c].x, vi[a][c]);
          }
      }
#pragma unroll
      for (int a = 0; a < 4; ++a)
#pragma unroll
        for (int c = 0; c < 4; ++c)
          Vb[g0 + 16 * a][g1 + 16 * c] = make_float2(
              vr[a][c] * mu, (m == 0) ? 0.0f : vi[a][c] * mu);
    }
    __syncthreads();
    // stage Wo tile [d][c] (Wb free; Y-GEMM below doesn't touch it)
    {
      const float2* wo = Rwo + (size_t)m * 32768 + (size_t)(h * 64) * 64;
      for (int k = tid; k < 4096; k += 256) Wb[k >> 6][k & 63] = wo[k];
    }
    // Y[s][d] = sum_t At[s][t] * V[t][d]
    {
      float yr[4][4] = {}, yi[4][4] = {};
#pragma unroll 4
      for (int t = 0; t < 64; ++t) {
        float av[4];
        float2 vv[4];
#pragma unroll
        for (int a = 0; a < 4; ++a) av[a] = At[g0 + 16 * a][t];
#pragma unroll
        for (int c = 0; c < 4; ++c) vv[c] = Vb[t][g1 + 16 * c];
#pragma unroll
        for (int a = 0; a < 4; ++a)
#pragma unroll
          for (int c = 0; c < 4; ++c) {
            yr[a][c] = fmaf(av[a], vv[c].x, yr[a][c]);
            yi[a][c] = fmaf(av[a], vv[c].y, yi[a][c]);
          }
      }
#pragma unroll
      for (int a = 0; a < 4; ++a)
#pragma unroll
        for (int c = 0; c < 4; ++c)
          Yb[g0 + 16 * a][g1 + 16 * c] = make_float2(yr[a][c], yi[a][c]);
    }
    __syncthreads();
    // Ff[s][c] += sum_d Y[s][d] * Wo[d][c] (complex)
    {
#pragma unroll 4
      for (int d = 0; d < 64; ++d) {
        float2 yv[4], wv2[4];
#pragma unroll
        for (int a = 0; a < 4; ++a) yv[a] = Yb[g0 + 16 * a][d];
#pragma unroll
        for (int c = 0; c < 4; ++c) wv2[c] = Wb[d][g1 + 16 * c];
#pragma unroll
        for (int a = 0; a < 4; ++a)
#pragma unroll
          for (int c = 0; c < 4; ++c) {
            fr[a][c] = fmaf(yv[a].x, wv2[c].x, fr[a][c]);
            fr[a][c] = fmaf(-yv[a].y, wv2[c].y, fr[a][c]);
            fi[a][c] = fmaf(yv[a].x, wv2[c].y, fi[a][c]);
            fi[a][c] = fmaf(yv[a].y, wv2[c].x, fi[a][c]);
          }
      }
    }
  }
#pragma unroll
  for (int a = 0; a < 4; ++a)
#pragma unroll
    for (int c = 0; c < 4; ++c)
      Ff[(((size_t)b * 64 + g0 + 16 * a) * 64 + (g1 + 16 * c)) * 256 + m] =
          make_float2(fr[a][c], fi[a][c]);
}

// ---------------- K5: inverse DFT to real field ----------------
__global__ __launch_bounds__(256) void k_idft(const float2* __restrict__ Ff,
                                              float* __restrict__ out) {
  __shared__ float2 Fm[256];
  __shared__ float2 g[32][17];
  __shared__ float2 tw[32];
  int f = blockIdx.x;
  int tid = threadIdx.x;
  if (tid < 32) {
    float a = (2.0f * PI_F / 32.0f) * (float)tid;
    tw[tid] = make_float2(cosf(a), sinf(a));
  }
  Fm[tid] = Ff[(size_t)f * 256 + tid];
  __syncthreads();
  for (int o = tid; o < 512; o += 256) {
    int x = o >> 4, q = o & 15;
    float gr = 0.f, gi = 0.f;
#pragma unroll
    for (int p = 0; p < 16; ++p) {
      float2 a = Fm[p * 16 + q];
      float2 w = tw[(p * x) & 31];
      gr += a.x * w.x - a.y * w.y;
      gi += a.x * w.y + a.y * w.x;
    }
    g[x][q] = make_float2(gr, gi);
  }
  __syncthreads();
  int x = tid >> 3, j0 = (tid & 7) * 4;
  float4 r;
  float* rr = &r.x;
#pragma unroll
  for (int jj = 0; jj < 4; ++jj) {
    int j = j0 + jj;
    float acc = 0.f;
#pragma unroll
    for (int q = 0; q < 16; ++q) {
      float2 gv = g[x][q];
      float2 w = tw[(q * j) & 31];
      acc += gv.x * w.x - gv.y * w.y;
    }
    rr[jj] = acc * (1.0f / 1024.0f);
  }
  *(float4*)(out + (size_t)f * 1024 + x * 32 + j0) = r;
}

// ======= fallback kernels (original, raw-weight reads) for small ws =======
__global__ __launch_bounds__(256) void k_scores(const float2* __restrict__ Xf,
                                                const float* __restrict__ wq_,
                                                const float* __restrict__ wk_,
                                                float* __restrict__ scores) {
  __shared__ float2 Xs[64][65];
  __shared__ float2 Wb[64][65];
  __shared__ float2 Qb[64][65];
  __shared__ float2 Kb[64][65];
  const float2* wq = (const float2*)wq_;
  const float2* wk = (const float2*)wk_;
  int chunk = blockIdx.x, h = blockIdx.y, b = blockIdx.z;
  int tid = threadIdx.x;
  int g0 = tid >> 4, g1 = tid & 15;
  int r0 = g0 * 4, c0 = g1 * 4;
  float sc[4][4] = {};
  for (int mm = 0; mm < 8; ++mm) {
    int m = chunk * 8 + mm;
    __syncthreads();
    {
      const float2* xs = Xf + ((size_t)b * 256 + m) * 4096;
      for (int k = tid; k < 4096; k += 256) Xs[k >> 6][k & 63] = xs[k];
      for (int k = tid; k < 4096; k += 256) {
        int i = k >> 6, d = k & 63;
        Wb[i][d] = wq[((size_t)i * 512 + h * 64 + d) * 256 + m];
      }
    }
    __syncthreads();
    {
      float qr[4][4] = {}, qi[4][4] = {};
      for (int i = 0; i < 64; ++i) {
        float2 xv[4], wv[4];
#pragma unroll
        for (int a = 0; a < 4; ++a) xv[a] = Xs[r0 + a][i];
#pragma unroll
        for (int c = 0; c < 4; ++c) wv[c] = Wb[i][c0 + c];
#pragma unroll
        for (int a = 0; a < 4; ++a)
#pragma unroll
          for (int c = 0; c < 4; ++c) {
            qr[a][c] = fmaf(xv[a].x, wv[c].x, qr[a][c]);
            qr[a][c] = fmaf(-xv[a].y, wv[c].y, qr[a][c]);
            qi[a][c] = fmaf(xv[a].x, wv[c].y, qi[a][c]);
            qi[a][c] = fmaf(xv[a].y, wv[c].x, qi[a][c]);
          }
      }
      float lam = (m == 0) ? 1.0f : (((m & 15) == 0) ? 0.5f : 2.0f);
#pragma unroll
      for (int a = 0; a < 4; ++a)
#pragma unroll
        for (int c = 0; c < 4; ++c)
          Qb[r0 + a][c0 + c] =
              make_float2(qr[a][c] * lam, (m == 0) ? 0.0f : qi[a][c] * lam);
    }
    __syncthreads();
    for (int k = tid; k < 4096; k += 256) {
      int i = k >> 6, d = k & 63;
      Wb[i][d] = wk[((size_t)i * 512 + h * 64 + d) * 256 + m];
    }
    __syncthreads();
    {
      float qr[4][4] = {}, qi[4][4] = {};
      for (int i = 0; i < 64; ++i) {
        float2 xv[4], wv[4];
#pragma unroll
        for (int a = 0; a < 4; ++a) xv[a] = Xs[r0 + a][i];
#pragma unroll
        for (int c = 0; c < 4; ++c) wv[c] = Wb[i][c0 + c];
#pragma unroll
        for (int a = 0; a < 4; ++a)
#pragma unroll
          for (int c = 0; c < 4; ++c) {
            qr[a][c] = fmaf(xv[a].x, wv[c].x, qr[a][c]);
            qr[a][c] = fmaf(-xv[a].y, wv[c].y, qr[a][c]);
            qi[a][c] = fmaf(xv[a].x, wv[c].y, qi[a][c]);
            qi[a][c] = fmaf(xv[a].y, wv[c].x, qi[a][c]);
          }
      }
#pragma unroll
      for (int a = 0; a < 4; ++a)
#pragma unroll
        for (int c = 0; c < 4; ++c)
          Kb[r0 + a][c0 + c] = make_float2(qr[a][c], qi[a][c]);
    }
    __syncthreads();
    {
      for (int d = 0; d < 64; ++d) {
        float2 qv[4], kv[4];
#pragma unroll
        for (int a = 0; a < 4; ++a) qv[a] = Qb[r0 + a][d];
#pragma unroll
        for (int c = 0; c < 4; ++c) kv[c] = Kb[c0 + c][d];
#pragma unroll
        for (int a = 0; a < 4; ++a)
#pragma unroll
          for (int c = 0; c < 4; ++c)
            sc[a][c] =
                fmaf(qv[a].x, kv[c].x, fmaf(qv[a].y, kv[c].y, sc[a][c]));
      }
    }
  }
  const float fac = 1.0f / 262144.0f;
  float* dst = scores + ((size_t)(b * 8 + h)) * 4096;
#pragma unroll
  for (int a = 0; a < 4; ++a)
#pragma unroll
    for (int c = 0; c < 4; ++c)
      atomicAdd(&dst[(r0 + a) * 64 + (c0 + c)], sc[a][c] * fac);
}

__global__ __launch_bounds__(256) void k_vpath(const float2* __restrict__ Xf,
                                               const float* __restrict__ wv_,
                                               const float* __restrict__ wo_,
                                               const float* __restrict__ attn,
                                               float2* __restrict__ Ff) {
  __shared__ float2 Xs[64][65];
  __shared__ float2 Wb[64][65];
  __shared__ float2 Vb[64][65];
  __shared__ float2 Yb[64][65];
  __shared__ float At[64][65];
  const float2* wv = (const float2*)wv_;
  const float2* wo = (const float2*)wo_;
  int m = blockIdx.x, b = blockIdx.y;
  int tid = threadIdx.x;
  int g0 = tid >> 4, g1 = tid & 15;
  int r0 = g0 * 4, c0 = g1 * 4;
  const float2* xs = Xf + ((size_t)b * 256 + m) * 4096;
  for (int k = tid; k < 4096; k += 256) Xs[k >> 6][k & 63] = xs[k];
  float fr[4][4] = {}, fi[4][4] = {};
  float mu = (m == 0) ? 1.0f : (((m & 15) == 0) ? 0.5f : 2.0f);
  for (int h = 0; h < 8; ++h) {
    __syncthreads();
    const float* at = attn + ((size_t)(b * 8 + h)) * 4096;
    for (int k = tid; k < 4096; k += 256) At[k >> 6][k & 63] = at[k];
    for (int k = tid; k < 4096; k += 256) {
      int i = k >> 6, d = k & 63;
      Wb[i][d] = wv[((size_t)i * 512 + h * 64 + d) * 256 + m];
    }
    __syncthreads();
    {
      float vr[4][4] = {}, vi[4][4] = {};
      for (int i = 0; i < 64; ++i) {
        float2 xv[4], wvv[4];
#pragma unroll
        for (int a = 0; a < 4; ++a) xv[a] = Xs[r0 + a][i];
#pragma unroll
        for (int c = 0; c < 4; ++c) wvv[c] = Wb[i][c0 + c];
#pragma unroll
        for (int a = 0; a < 4; ++a)
#pragma unroll
          for (int c = 0; c < 4; ++c) {
            vr[a][c] = fmaf(xv[a].x, wvv[c].x, vr[a][c]);
            vr[a][c] = fmaf(-xv[a].y, wvv[c].y, vr[a][c]);
            vi[a][c] = fmaf(xv[a].x, wvv[c].y, vi[a][c]);
            vi[a][c] = fmaf(xv[a].y, wvv[c].x, vi[a][c]);
          }
      }
#pragma unroll
      for (int a = 0; a < 4; ++a)
#pragma unroll
        for (int c = 0; c < 4; ++c)
          Vb[r0 + a][c0 + c] = make_float2(vr[a][c] * mu,
                                           (m == 0) ? 0.0f : vi[a][c] * mu);
    }
    __syncthreads();
    for (int k = tid; k < 4096; k += 256) {
      int d = k >> 6, c = k & 63;
      Wb[d][c] = wo[((size_t)(h * 64 + d) * 64 + c) * 256 + m];
    }
    {
      float yr[4][4] = {}, yi[4][4] = {};
      for (int t = 0; t < 64; ++t) {
        float av[4];
        float2 vv[4];
#pragma unroll
        for (int a = 0; a < 4; ++a) av[a] = At[r0 + a][t];
#pragma unroll
        for (int c = 0; c < 4; ++c) vv[c] = Vb[t][c0 + c];
#pragma unroll
        for (int a = 0; a < 4; ++a)
#pragma unroll
          for (int c = 0; c < 4; ++c) {
            yr[a][c] = fmaf(av[a], vv[c].x, yr[a][c]);
            yi[a][c] = fmaf(av[a], vv[c].y, yi[a][c]);
          }
      }
#pragma unroll
      for (int a = 0; a < 4; ++a)
#pragma unroll
        for (int c = 0; c < 4; ++c)
          Yb[r0 + a][c0 + c] = make_float2(yr[a][c], yi[a][c]);
    }
    __syncthreads();
    {
      for (int d = 0; d < 64; ++d) {
        float2 yv[4], wv2[4];
#pragma unroll
        for (int a = 0; a < 4; ++a) yv[a] = Yb[r0 + a][d];
#pragma unroll
        for (int c = 0; c < 4; ++c) wv2[c] = Wb[d][c0 + c];
#pragma unroll
        for (int a = 0; a < 4; ++a)
#pragma unroll
          for (int c = 0; c < 4; ++c) {
            fr[a][c] = fmaf(yv[a].x, wv2[c].x, fr[a][c]);
            fr[a][c] = fmaf(-yv[a].y, wv2[c].y, fr[a][c]);
            fi[a][c] = fmaf(yv[a].x, wv2[c].y, fi[a][c]);
            fi[a][c] = fmaf(yv[a].y, wv2[c].x, fi[a][c]);
          }
      }
    }
  }
#pragma unroll
  for (int a = 0; a < 4; ++a)
#pragma unroll
    for (int c = 0; c < 4; ++c)
      Ff[(((size_t)b * 64 + r0 + a) * 64 + (c0 + c)) * 256 + m] =
          make_float2(fr[a][c], fi[a][c]);
}

extern "C" void kernel_launch(void* const* d_in, const int* in_sizes, int n_in,
                              void* d_out, int out_size, void* d_ws,
                              size_t ws_size, hipStream_t stream) {
  const float* seq = (const float*)d_in[0];
  const float* wq = (const float*)d_in[1];
  const float* wk = (const float*)d_in[2];
  const float* wv = (const float*)d_in[3];
  const float* wo = (const float*)d_in[4];
  const float* w1 = (const float*)d_in[5];
  const float* b1 = (const float*)d_in[6];
  const float* w2 = (const float*)d_in[7];
  const float* b2 = (const float*)d_in[8];
  float* out = (float*)d_out;

  char* ws = (char*)d_ws;
  float2* Xf = (float2*)(ws);                      // 16,777,216 B
  float* scores = (float*)(ws + 16777216);         //    262,144 B
  float2* Ff = (float2*)(ws + 16777216 + 262144);  // 16,777,216 B
  const size_t base = 16777216ull + 262144 + 16777216;
  const size_t need = base + 2ull * 67108864;

  hipMemsetAsync(scores, 0, 262144, stream);
  k_dft<<<8192, 256, 0, stream>>>(seq, Xf);

  if (ws_size >= need) {
    float2* R1 = (float2*)(ws + base);
    float2* R2 = (float2*)(ws + base + 67108864ull);
    k_repack<<<512, 256, 0, stream>>>((const float2*)wq, R1);
    k_repack<<<512, 256, 0, stream>>>((const float2*)wk, R2);
    k_scores_r<<<dim3(32, 8, 2), 256, 0, stream>>>(Xf, R1, R2, scores);
    k_softmax<<<1024, 64, 0, stream>>>(scores, w1, b1, w2, b2);
    k_repack<<<512, 256, 0, stream>>>((const float2*)wv, R1);
    k_repack<<<512, 256, 0, stream>>>((const float2*)wo, R2);
    k_vpath_r<<<dim3(256, 2), 256, 0, stream>>>(Xf, R1, R2, scores, Ff);
  } else {
    k_scores<<<dim3(32, 8, 2), 256, 0, stream>>>(Xf, wq, wk, scores);
    k_softmax<<<1024, 64, 0, stream>>>(scores, w1, b1, w2, b2);
    k_vpath<<<dim3(256, 2), 256, 0, stream>>>(Xf, wv, wo, scores, Ff);
  }
  k_idft<<<8192, 256, 0, stream>>>(Ff, out);
}

// Round 3
// 299.722 us; speedup vs baseline: 5.1218x; 4.4577x over previous
//
#include <hip/hip_runtime.h>
#include <math.h>

// B=2, S=64, C=64, NH=8, H=W=32, M1=M2=16 (256 modes), mode m=p*16+q.
// lambda/mu: m==0 -> 1 (imag zeroed), m%16==0 -> 0.5, else 2.

#define PI_F 3.14159265358979323846f

typedef _Float16 f16;
typedef f16 f16x8 __attribute__((ext_vector_type(8)));
typedef f16 f16x4 __attribute__((ext_vector_type(4)));
typedef float f32x4 __attribute__((ext_vector_type(4)));

#define MFMA(a, b, c) __builtin_amdgcn_mfma_f32_16x16x32_f16(a, b, c, 0, 0, 0)

// byte offset of a 16B slot in an 8KB [64 rows][64 f16] plane, XOR-swizzled
__device__ __forceinline__ int swz128(int row, int slot) {
  return (row << 7) + (((slot) ^ (row & 7)) << 4);
}
// byte offset of one f16 element (same swizzle)
__device__ __forceinline__ int swzel(int row, int col) {
  return (row << 7) + ((((col) >> 3) ^ (row & 7)) << 4) + (((col) & 7) << 1);
}

// ---------------- K1: forward DFT -> fp16 re/im planes [b][m][s*64+i] ------
__global__ __launch_bounds__(256) void k_dft(const float* __restrict__ seq,
                                             f16* __restrict__ Xr,
                                             f16* __restrict__ Xi) {
  __shared__ float fld[32][33];
  __shared__ float2 tb[32][17];
  __shared__ float2 tw[32];
  int f = blockIdx.x;
  int tid = threadIdx.x;
  if (tid < 32) {
    float a = (2.0f * PI_F / 32.0f) * (float)tid;
    tw[tid] = make_float2(cosf(a), sinf(a));
  }
  const float4* s4 = (const float4*)(seq + (size_t)f * 1024);
  float4 v = s4[tid];
  int x0 = tid >> 3, y0 = (tid & 7) * 4;
  fld[x0][y0 + 0] = v.x; fld[x0][y0 + 1] = v.y;
  fld[x0][y0 + 2] = v.z; fld[x0][y0 + 3] = v.w;
  __syncthreads();
  for (int o = tid; o < 512; o += 256) {
    int x = o >> 4, q = o & 15;
    float re = 0.f, im = 0.f;
#pragma unroll
    for (int y = 0; y < 32; ++y) {
      float val = fld[x][y];
      float2 w = tw[(q * y) & 31];
      re = fmaf(val, w.x, re);
      im = fmaf(val, -w.y, im);
    }
    tb[x][q] = make_float2(re, im);
  }
  __syncthreads();
  int p = tid >> 4, q = tid & 15;
  float re = 0.f, im = 0.f;
#pragma unroll
  for (int x = 0; x < 32; ++x) {
    float2 t = tb[x][q];
    float2 w = tw[(p * x) & 31];
    re += w.x * t.x + w.y * t.y;
    im += w.x * t.y - w.y * t.x;
  }
  int b = f >> 12;
  int si = f & 4095;
  size_t o = (size_t)(b * 256 + tid) * 4096 + si;
  Xr[o] = (f16)re;
  Xi[o] = (f16)im;
}

// ---------------- K-repack: [a*B+b][256] float2 -> fp16 planes [m][b*A+a] --
// wq/wk/wv: A=64(i), B=512(hd) -> plane rows hd (the [d][i] transposed tile)
// wo:       A=512(hd), B=64(c) -> plane rows c  (the [c][d] transposed tile)
__global__ __launch_bounds__(256) void k_repackh(const float2* __restrict__ in,
                                                 f16* __restrict__ outR,
                                                 f16* __restrict__ outI,
                                                 int A, int B) {
  __shared__ float2 t[64][65];
  int tid = threadIdx.x;
  int m0 = blockIdx.x * 64, a0 = blockIdx.y * 64, bb = blockIdx.z;
  for (int k = tid; k < 4096; k += 256) {
    int ai = k >> 6, mi = k & 63;
    t[ai][mi] = in[((size_t)(a0 + ai) * B + bb) * 256 + m0 + mi];
  }
  __syncthreads();
  for (int k = tid; k < 4096; k += 256) {
    int mi = k >> 6, ai = k & 63;
    float2 v = t[ai][mi];
    size_t o = (size_t)(m0 + mi) * 32768 + (size_t)bb * A + a0 + ai;
    outR[o] = (f16)v.x;
    outI[o] = (f16)v.y;
  }
}

// ---------------- K2: MFMA scores -----------------------------------------
// grid (32 chunks, 8 h, 2 b), 256 thr (4 waves, 2x2 of 32x32 tiles).
__global__ __launch_bounds__(256, 2) void k_scores_m(
    const f16* __restrict__ Xr, const f16* __restrict__ Xi,
    const f16* __restrict__ Qwr, const f16* __restrict__ Qwi,
    const f16* __restrict__ Kwr, const f16* __restrict__ Kwi,
    float* __restrict__ scores) {
  __shared__ __align__(16) unsigned char smem[65536];
  const int P_WQR = 0, P_WQI = 8192, P_WKR = 16384, P_WKI = 24576;
  const int P_QR = 32768, P_QI = 40960, P_KR = 49152, P_KI = 57344;
  int tid = threadIdx.x;
  int w = tid >> 6, lane = tid & 63, r = lane & 15, g = lane >> 4;
  int wr = w >> 1, wc = w & 1;
  int chunk = blockIdx.x, h = blockIdx.y, b = blockIdx.z;
  f32x4 S[2][2] = {};
  for (int mm = 0; mm < 8; ++mm) {
    int m = chunk * 8 + mm;
    // X fragments straight from global (rows 32*wr.., k-groups per MFMA spec)
    const f16x8* xr8 = (const f16x8*)Xr + (size_t)(b * 256 + m) * 512;
    const f16x8* xi8 = (const f16x8*)Xi + (size_t)(b * 256 + m) * 512;
    f16x8 axr[2][2], axi[2][2], axiN[2][2];
#pragma unroll
    for (int rt = 0; rt < 2; ++rt)
#pragma unroll
      for (int kt = 0; kt < 2; ++kt) {
        int idx = (32 * wr + rt * 16 + r) * 8 + kt * 4 + g;
        axr[rt][kt] = xr8[idx];
        axi[rt][kt] = xi8[idx];
        axiN[rt][kt] = -axi[rt][kt];
      }
    // stage Wq/Wk transposed planes (contiguous 8KB each)
    const float4* gqr = (const float4*)Qwr + (size_t)m * 4096 + h * 512;
    const float4* gqi = (const float4*)Qwi + (size_t)m * 4096 + h * 512;
    const float4* gkr = (const float4*)Kwr + (size_t)m * 4096 + h * 512;
    const float4* gki = (const float4*)Kwi + (size_t)m * 4096 + h * 512;
#pragma unroll
    for (int it = 0; it < 2; ++it) {
      int s = tid + it * 256;
      int row = s >> 3, sl = s & 7;
      int lo = swz128(row, sl);
      *(float4*)(smem + P_WQR + lo) = gqr[s];
      *(float4*)(smem + P_WQI + lo) = gqi[s];
      *(float4*)(smem + P_WKR + lo) = gkr[s];
      *(float4*)(smem + P_WKI + lo) = gki[s];
    }
    __syncthreads();
    float lam = (m == 0) ? 1.0f : (((m & 15) == 0) ? 0.5f : 2.0f);
    // ---- Q = X*Wq (complex) ----
    {
      f32x4 cr[2][2] = {}, ci[2][2] = {};
#pragma unroll
      for (int ct = 0; ct < 2; ++ct)
#pragma unroll
        for (int kt = 0; kt < 2; ++kt) {
          int lo = swz128(32 * wc + ct * 16 + r, kt * 4 + g);
          f16x8 bwr = *(const f16x8*)(smem + P_WQR + lo);
          f16x8 bwi = *(const f16x8*)(smem + P_WQI + lo);
#pragma unroll
          for (int rt = 0; rt < 2; ++rt) {
            cr[rt][ct] = MFMA(axr[rt][kt], bwr, cr[rt][ct]);
            cr[rt][ct] = MFMA(axiN[rt][kt], bwi, cr[rt][ct]);
            ci[rt][ct] = MFMA(axr[rt][kt], bwi, ci[rt][ct]);
            ci[rt][ct] = MFMA(axi[rt][kt], bwr, ci[rt][ct]);
          }
        }
#pragma unroll
      for (int rt = 0; rt < 2; ++rt)
#pragma unroll
        for (int ct = 0; ct < 2; ++ct)
#pragma unroll
          for (int j = 0; j < 4; ++j) {
            int row = 32 * wr + rt * 16 + g * 4 + j;
            int col = 32 * wc + ct * 16 + r;
            *(f16*)(smem + P_QR + swzel(row, col)) = (f16)(cr[rt][ct][j] * lam);
            *(f16*)(smem + P_QI + swzel(row, col)) =
                (m == 0) ? (f16)0.f : (f16)(ci[rt][ct][j] * lam);
          }
    }
    // ---- K = X*Wk (complex) ----
    {
      f32x4 cr[2][2] = {}, ci[2][2] = {};
#pragma unroll
      for (int ct = 0; ct < 2; ++ct)
#pragma unroll
        for (int kt = 0; kt < 2; ++kt) {
          int lo = swz128(32 * wc + ct * 16 + r, kt * 4 + g);
          f16x8 bwr = *(const f16x8*)(smem + P_WKR + lo);
          f16x8 bwi = *(const f16x8*)(smem + P_WKI + lo);
#pragma unroll
          for (int rt = 0; rt < 2; ++rt) {
            cr[rt][ct] = MFMA(axr[rt][kt], bwr, cr[rt][ct]);
            cr[rt][ct] = MFMA(axiN[rt][kt], bwi, cr[rt][ct]);
            ci[rt][ct] = MFMA(axr[rt][kt], bwi, ci[rt][ct]);
            ci[rt][ct] = MFMA(axi[rt][kt], bwr, ci[rt][ct]);
          }
        }
#pragma unroll
      for (int rt = 0; rt < 2; ++rt)
#pragma unroll
        for (int ct = 0; ct < 2; ++ct)
#pragma unroll
          for (int j = 0; j < 4; ++j) {
            int row = 32 * wr + rt * 16 + g * 4 + j;
            int col = 32 * wc + ct * 16 + r;
            *(f16*)(smem + P_KR + swzel(row, col)) = (f16)cr[rt][ct][j];
            *(f16*)(smem + P_KI + swzel(row, col)) = (f16)ci[rt][ct][j];
          }
    }
    __syncthreads();
    // ---- S += Qr*Kr^T + Qi*Ki^T ----
    {
      f16x8 aqr[2][2], aqi[2][2];
#pragma unroll
      for (int rt = 0; rt < 2; ++rt)
#pragma unroll
        for (int kt = 0; kt < 2; ++kt) {
          int lo = swz128(32 * wr + rt * 16 + r, kt * 4 + g);
          aqr[rt][kt] = *(const f16x8*)(smem + P_QR + lo);
          aqi[rt][kt] = *(const f16x8*)(smem + P_QI + lo);
        }
#pragma unroll
      for (int ct = 0; ct < 2; ++ct)
#pragma unroll
        for (int kt = 0; kt < 2; ++kt) {
          int lo = swz128(32 * wc + ct * 16 + r, kt * 4 + g);
          f16x8 bkr = *(const f16x8*)(smem + P_KR + lo);
          f16x8 bki = *(const f16x8*)(smem + P_KI + lo);
#pragma unroll
          for (int rt = 0; rt < 2; ++rt) {
            S[rt][ct] = MFMA(aqr[rt][kt], bkr, S[rt][ct]);
            S[rt][ct] = MFMA(aqi[rt][kt], bki, S[rt][ct]);
          }
        }
    }
  }
  const float fac = 1.0f / 262144.0f;
  float* dst = scores + ((size_t)(b * 8 + h)) * 4096;
#pragma unroll
  for (int rt = 0; rt < 2; ++rt)
#pragma unroll
    for (int ct = 0; ct < 2; ++ct)
#pragma unroll
      for (int j = 0; j < 4; ++j) {
        int s_ = 32 * wr + rt * 16 + g * 4 + j;
        int t_ = 32 * wc + ct * 16 + r;
        atomicAdd(&dst[s_ * 64 + t_], S[rt][ct][j] * fac);
      }
}

// ---------------- K3: log-CPB bias + softmax -> fp16 attn -----------------
__global__ __launch_bounds__(64) void k_softmax(const float* __restrict__ scores,
                                                const float* __restrict__ w1,
                                                const float* __restrict__ b1,
                                                const float* __restrict__ w2,
                                                const float* __restrict__ b2,
                                                f16* __restrict__ at) {
  int id = blockIdx.x;
  int s = id & 63;
  int h = (id >> 6) & 7;
  int t = threadIdx.x;
  float d0 = (float)((s >> 3) - (t >> 3)) * (8.0f / 7.0f);
  float d1 = (float)((s & 7) - (t & 7)) * (8.0f / 7.0f);
  float a0 = log2f(fabsf(d0) + 1.0f) * (1.0f / 3.0f);
  float a1 = log2f(fabsf(d1) + 1.0f) * (1.0f / 3.0f);
  float r0 = (d0 < 0.f) ? -a0 : a0;
  float r1 = (d1 < 0.f) ? -a1 : a1;
  float acc = b2[h];
  for (int c = 0; c < 64; ++c) {
    float hv = fmaf(r0, w1[c], fmaf(r1, w1[64 + c], b1[c]));
    hv = fmaxf(hv, 0.0f);
    acc = fmaf(hv, w2[c * 8 + h], acc);
  }
  float bias = 16.0f / (1.0f + expf(-acc));
  size_t base = (size_t)id * 64;
  float v = scores[base + t] + bias;
  float mx = v;
  for (int o = 32; o; o >>= 1) mx = fmaxf(mx, __shfl_xor(mx, o));
  float e = expf(v - mx);
  float sm = e;
  for (int o = 32; o; o >>= 1) sm += __shfl_xor(sm, o);
  at[base + t] = (f16)(e / sm);
}

// ---------------- K4: MFMA V-path -----------------------------------------
// grid (256 m, 2 b), 256 thr. F accumulated in regs across 8 heads.
__global__ __launch_bounds__(256, 2) void k_vpath_m(
    const f16* __restrict__ Xr, const f16* __restrict__ Xi,
    const f16* __restrict__ Vwr, const f16* __restrict__ Vwi,
    const f16* __restrict__ Owr, const f16* __restrict__ Owi,
    const f16* __restrict__ At, float2* __restrict__ Ff) {
  __shared__ __align__(16) unsigned char smem[73728];
  const int P_WVR = 0, P_WVI = 8192, P_WOR = 16384, P_WOI = 24576;
  const int P_VTR = 32768, P_VTI = 40960, P_YR = 49152, P_YI = 57344;
  const int P_AT = 65536;
  int tid = threadIdx.x;
  int w = tid >> 6, lane = tid & 63, r = lane & 15, g = lane >> 4;
  int wr = w >> 1, wc = w & 1;
  int m = blockIdx.x, b = blockIdx.y;
  // X fragments once per block
  const f16x8* xr8 = (const f16x8*)Xr + (size_t)(b * 256 + m) * 512;
  const f16x8* xi8 = (const f16x8*)Xi + (size_t)(b * 256 + m) * 512;
  f16x8 axr[2][2], axi[2][2], axiN[2][2];
#pragma unroll
  for (int rt = 0; rt < 2; ++rt)
#pragma unroll
    for (int kt = 0; kt < 2; ++kt) {
      int idx = (32 * wr + rt * 16 + r) * 8 + kt * 4 + g;
      axr[rt][kt] = xr8[idx];
      axi[rt][kt] = xi8[idx];
      axiN[rt][kt] = -axi[rt][kt];
    }
  float mu = (m == 0) ? 1.0f : (((m & 15) == 0) ? 0.5f : 2.0f);
  f32x4 fr[2][2] = {}, fi_[2][2] = {};
  for (int h = 0; h < 8; ++h) {
    __syncthreads();  // prev F-GEMM (reads Y/WO) done before restaging
    const float4* gvr = (const float4*)Vwr + (size_t)m * 4096 + h * 512;
    const float4* gvi = (const float4*)Vwi + (size_t)m * 4096 + h * 512;
    const float4* gor = (const float4*)Owr + (size_t)m * 4096 + h * 8;
    const float4* goi = (const float4*)Owi + (size_t)m * 4096 + h * 8;
    const float4* gat = (const float4*)At + (size_t)(b * 8 + h) * 512;
#pragma unroll
    for (int it = 0; it < 2; ++it) {
      int s = tid + it * 256;
      int row = s >> 3, sl = s & 7;
      int lo = swz128(row, sl);
      *(float4*)(smem + P_WVR + lo) = gvr[s];
      *(float4*)(smem + P_WVI + lo) = gvi[s];
      *(float4*)(smem + P_WOR + lo) = gor[row * 64 + sl];
      *(float4*)(smem + P_WOI + lo) = goi[row * 64 + sl];
      *(float4*)(smem + P_AT + lo) = gat[s];
    }
    __syncthreads();
    // ---- V = mu * X*Wv (complex, DC imag zero), store transposed VT[d][t]
    {
      f32x4 vr[2][2] = {}, vi[2][2] = {};
#pragma unroll
      for (int ct = 0; ct < 2; ++ct)
#pragma unroll
        for (int kt = 0; kt < 2; ++kt) {
          int lo = swz128(32 * wc + ct * 16 + r, kt * 4 + g);
          f16x8 bwr = *(const f16x8*)(smem + P_WVR + lo);
          f16x8 bwi = *(const f16x8*)(smem + P_WVI + lo);
#pragma unroll
          for (int rt = 0; rt < 2; ++rt) {
            vr[rt][ct] = MFMA(axr[rt][kt], bwr, vr[rt][ct]);
            vr[rt][ct] = MFMA(axiN[rt][kt], bwi, vr[rt][ct]);
            vi[rt][ct] = MFMA(axr[rt][kt], bwi, vi[rt][ct]);
            vi[rt][ct] = MFMA(axi[rt][kt], bwr, vi[rt][ct]);
          }
        }
#pragma unroll
      for (int rt = 0; rt < 2; ++rt)
#pragma unroll
        for (int ct = 0; ct < 2; ++ct) {
          int drow = 32 * wc + ct * 16 + r;      // d (tile col)
          int t0 = 32 * wr + rt * 16 + g * 4;    // 4 consecutive t (tile rows)
          f16x4 pr, pi;
#pragma unroll
          for (int j = 0; j < 4; ++j) {
            pr[j] = (f16)(vr[rt][ct][j] * mu);
            pi[j] = (m == 0) ? (f16)0.f : (f16)(vi[rt][ct][j] * mu);
          }
          int lo = swzel(drow, t0);  // 8B-aligned (t0 % 4 == 0)
          *(f16x4*)(smem + P_VTR + lo) = pr;
          *(f16x4*)(smem + P_VTI + lo) = pi;
        }
    }
    __syncthreads();
    // ---- Y = At * V ----
    {
      f16x8 aat[2][2];
#pragma unroll
      for (int rt = 0; rt < 2; ++rt)
#pragma unroll
        for (int kt = 0; kt < 2; ++kt)
          aat[rt][kt] = *(const f16x8*)(
              smem + P_AT + swz128(32 * wr + rt * 16 + r, kt * 4 + g));
      f32x4 yr[2][2] = {}, yi[2][2] = {};
#pragma unroll
      for (int ct = 0; ct < 2; ++ct)
#pragma unroll
        for (int kt = 0; kt < 2; ++kt) {
          int lo = swz128(32 * wc + ct * 16 + r, kt * 4 + g);
          f16x8 bvr = *(const f16x8*)(smem + P_VTR + lo);
          f16x8 bvi = *(const f16x8*)(smem + P_VTI + lo);
#pragma unroll
          for (int rt = 0; rt < 2; ++rt) {
            yr[rt][ct] = MFMA(aat[rt][kt], bvr, yr[rt][ct]);
            yi[rt][ct] = MFMA(aat[rt][kt], bvi, yi[rt][ct]);
          }
        }
#pragma unroll
      for (int rt = 0; rt < 2; ++rt)
#pragma unroll
        for (int ct = 0; ct < 2; ++ct)
#pragma unroll
          for (int j = 0; j < 4; ++j) {
            int row = 32 * wr + rt * 16 + g * 4 + j;
            int col = 32 * wc + ct * 16 + r;
            *(f16*)(smem + P_YR + swzel(row, col)) = (f16)yr[rt][ct][j];
            *(f16*)(smem + P_YI + swzel(row, col)) = (f16)yi[rt][ct][j];
          }
    }
    __syncthreads();
    // ---- F += Y * Wo (complex) ----
    {
      f16x8 ayr[2][2], ayi[2][2], ayiN[2][2];
#pragma unroll
      for (int rt = 0; rt < 2; ++rt)
#pragma unroll
        for (int kt = 0; kt < 2; ++kt) {
          int lo = swz128(32 * wr + rt * 16 + r, kt * 4 + g);
          ayr[rt][kt] = *(const f16x8*)(smem + P_YR + lo);
          ayi[rt][kt] = *(const f16x8*)(smem + P_YI + lo);
          ayiN[rt][kt] = -ayi[rt][kt];
        }
#pragma unroll
      for (int ct = 0; ct < 2; ++ct)
#pragma unroll
        for (int kt = 0; kt < 2; ++kt) {
          int lo = swz128(32 * wc + ct * 16 + r, kt * 4 + g);
          f16x8 bor = *(const f16x8*)(smem + P_WOR + lo);
          f16x8 boi = *(const f16x8*)(smem + P_WOI + lo);
#pragma unroll
          for (int rt = 0; rt < 2; ++rt) {
            fr[rt][ct] = MFMA(ayr[rt][kt], bor, fr[rt][ct]);
            fr[rt][ct] = MFMA(ayiN[rt][kt], boi, fr[rt][ct]);
            fi_[rt][ct] = MFMA(ayr[rt][kt], boi, fi_[rt][ct]);
            fi_[rt][ct] = MFMA(ayi[rt][kt], bor, fi_[rt][ct]);
          }
        }
    }
  }
#pragma unroll
  for (int rt = 0; rt < 2; ++rt)
#pragma unroll
    for (int ct = 0; ct < 2; ++ct)
#pragma unroll
      for (int j = 0; j < 4; ++j) {
        int s_ = 32 * wr + rt * 16 + g * 4 + j;
        int c_ = 32 * wc + ct * 16 + r;
        Ff[(((size_t)(b * 64 + s_)) * 64 + c_) * 256 + m] =
            make_float2(fr[rt][ct][j], fi_[rt][ct][j]);
      }
}

// ---------------- K5: inverse DFT -----------------------------------------
__global__ __launch_bounds__(256) void k_idft(const float2* __restrict__ Ff,
                                              float* __restrict__ out) {
  __shared__ float2 Fm[256];
  __shared__ float2 g[32][17];
  __shared__ float2 tw[32];
  int f = blockIdx.x;
  int tid = threadIdx.x;
  if (tid < 32) {
    float a = (2.0f * PI_F / 32.0f) * (float)tid;
    tw[tid] = make_float2(cosf(a), sinf(a));
  }
  Fm[tid] = Ff[(size_t)f * 256 + tid];
  __syncthreads();
  for (int o = tid; o < 512; o += 256) {
    int x = o >> 4, q = o & 15;
    float gr = 0.f, gi = 0.f;
#pragma unroll
    for (int p = 0; p < 16; ++p) {
      float2 a = Fm[p * 16 + q];
      float2 w = tw[(p * x) & 31];
      gr += a.x * w.x - a.y * w.y;
      gi += a.x * w.y + a.y * w.x;
    }
    g[x][q] = make_float2(gr, gi);
  }
  __syncthreads();
  int x = tid >> 3, j0 = (tid & 7) * 4;
  float4 r;
  float* rr = &r.x;
#pragma unroll
  for (int jj = 0; jj < 4; ++jj) {
    int j = j0 + jj;
    float acc = 0.f;
#pragma unroll
    for (int q = 0; q < 16; ++q) {
      float2 gv = g[x][q];
      float2 w = tw[(q * j) & 31];
      acc += gv.x * w.x - gv.y * w.y;
    }
    rr[jj] = acc * (1.0f / 1024.0f);
  }
  *(float4*)(out + (size_t)f * 1024 + x * 32 + j0) = r;
}

extern "C" void kernel_launch(void* const* d_in, const int* in_sizes, int n_in,
                              void* d_out, int out_size, void* d_ws,
                              size_t ws_size, hipStream_t stream) {
  const float* seq = (const float*)d_in[0];
  const float2* wq = (const float2*)d_in[1];
  const float2* wk = (const float2*)d_in[2];
  const float2* wv = (const float2*)d_in[3];
  const float2* wo = (const float2*)d_in[4];
  const float* w1 = (const float*)d_in[5];
  const float* b1 = (const float*)d_in[6];
  const float* w2 = (const float*)d_in[7];
  const float* b2 = (const float*)d_in[8];
  float* out = (float*)d_out;

  char* ws = (char*)d_ws;
  f16* Xr = (f16*)(ws + 0);                  //  4,194,304 B
  f16* Xi = (f16*)(ws + 4194304);            //  4,194,304 B
  float* scores = (float*)(ws + 8388608);    //    262,144 B
  f16* At = (f16*)(ws + 8650752);            //    131,072 B
  float2* Ff = (float2*)(ws + 8781824);      // 16,777,216 B
  f16* P0r = (f16*)(ws + 25559040);          // 16,777,216 B each
  f16* P0i = (f16*)(ws + 42336256);
  f16* P1r = (f16*)(ws + 59113472);
  f16* P1i = (f16*)(ws + 75890688);          // ends 92,667,904 B

  hipMemsetAsync(scores, 0, 262144, stream);
  k_dft<<<8192, 256, 0, stream>>>(seq, Xr, Xi);

  k_repackh<<<dim3(4, 1, 512), 256, 0, stream>>>(wq, P0r, P0i, 64, 512);
  k_repackh<<<dim3(4, 1, 512), 256, 0, stream>>>(wk, P1r, P1i, 64, 512);
  k_scores_m<<<dim3(32, 8, 2), 256, 0, stream>>>(Xr, Xi, P0r, P0i, P1r, P1i,
                                                 scores);
  k_softmax<<<1024, 64, 0, stream>>>(scores, w1, b1, w2, b2, At);
  k_repackh<<<dim3(4, 1, 512), 256, 0, stream>>>(wv, P0r, P0i, 64, 512);
  k_repackh<<<dim3(4, 8, 64), 256, 0, stream>>>(wo, P1r, P1i, 512, 64);
  k_vpath_m<<<dim3(256, 2), 256, 0, stream>>>(Xr, Xi, P0r, P0i, P1r, P1i, At,
                                              Ff);
  k_idft<<<8192, 256, 0, stream>>>(Ff, out);
}